// Round 6
// baseline (66.705 us; speedup 1.0000x reference)
//
#include <hip/hip_runtime.h>

#define BB 16
#define NN 300
#define PP 100
#define LL 32
#define HH 768
#define WW 768
#define BAND 8                  // rows per band-block
#define NBAND (HH / BAND)       // 96
#define PSTR 772                // LDS row stride in floats (16B-aligned)
#define NDETBLK 19              // ceil(4800/256)

__device__ __forceinline__ float relu_f(float x) { return fmaxf(x, 0.f); }

// ---------------------------------------------------------------------------
// K0: per-box metadata (conf-softmax + int pixel coords), computed once.
// metaX = x1 | ((x2-1)<<16); metaY = y1 | (y2<<16); 0 if invalid (empty range).
// ---------------------------------------------------------------------------
__global__ __launch_bounds__(256) void k_meta(const float* __restrict__ det_boxes,
                                              const float* __restrict__ logits,
                                              int* __restrict__ metaX,
                                              int* __restrict__ metaY) {
    const int idx = blockIdx.x * 256 + threadIdx.x;
    if (idx >= BB * NN) return;
    const float* lg = logits + (size_t)idx * 7;
    float m = lg[0];
    #pragma unroll
    for (int i = 1; i < 7; ++i) m = fmaxf(m, lg[i]);
    float sum = 0.f;
    #pragma unroll
    for (int i = 0; i < 7; ++i) sum += expf(lg[i] - m);
    float conf = 1.f / sum;

    const float* bxp = det_boxes + (size_t)idx * 4;
    float cx = bxp[0], cy = bxp[1], w = bxp[2], h = bxp[3];
    int x1 = (int)floorf((cx - w * 0.5f) * (float)WW);
    int y1 = (int)floorf((cy - h * 0.5f) * (float)HH);
    int x2 = (int)floorf((cx + w * 0.5f) * (float)WW);
    int y2 = (int)floorf((cy + h * 0.5f) * (float)HH);
    x1 = min(max(x1, 0), WW - 1); y1 = min(max(y1, 0), HH - 1);
    x2 = min(max(x2, 0), WW - 1); y2 = min(max(y2, 0), HH - 1);
    bool valid = (conf >= 0.3f) && (x2 > x1) && (y2 > y1);
    metaX[idx] = valid ? (x1 | ((x2 - 1) << 16)) : 0;
    metaY[idx] = valid ? (y1 | (y2 << 16)) : 0;
}

// ---------------------------------------------------------------------------
// K1: one block per (batch, 8-row band). Phase A: row prefixes into LDS.
// Lane l owns 12 contiguous floats -> 11 register adds + ONE 6-step wave scan
// per row (no chunk carry). Phase B: thread-per-box LDS lookups. No atomics.
// Grid: 1536 blocks of 256; LDS 24.7KB -> 6 blocks/CU (24 waves/CU).
// ---------------------------------------------------------------------------
__global__ __launch_bounds__(256, 6) void k_band(const float* __restrict__ seg,
                                                 const int* __restrict__ metaX,
                                                 const int* __restrict__ metaY,
                                                 float* __restrict__ detPartial) {
    const int blk  = blockIdx.x;
    const int b    = blk / NBAND;
    const int band = blk % NBAND;
    const int y0   = band * BAND;
    const int t    = threadIdx.x;
    const int wave = t >> 6, lane = t & 63;

    __shared__ float P[BAND * PSTR];   // 24704 B

    // ---- Phase A: 4 waves x 2 rows ----------------------------------------
    #pragma unroll
    for (int rr = 0; rr < 2; ++rr) {
        const int r = wave * 2 + rr;
        const int y = y0 + r;
        const float* p1 = seg + ((size_t)(b * 3 + 1) * HH + y) * WW + 12 * lane;
        const float* p2 = seg + ((size_t)(b * 3 + 2) * HH + y) * WW + 12 * lane;
        float4 A0 = *(const float4*)(p1);
        float4 A1 = *(const float4*)(p1 + 4);
        float4 A2 = *(const float4*)(p1 + 8);
        float4 B0 = *(const float4*)(p2);
        float4 B1 = *(const float4*)(p2 + 4);
        float4 B2 = *(const float4*)(p2 + 8);
        // local inclusive prefix over 12 diffs (registers, static)
        float r0  = B0.x - A0.x;
        float r1  = r0 + (B0.y - A0.y);
        float r2  = r1 + (B0.z - A0.z);
        float r3  = r2 + (B0.w - A0.w);
        float r4  = r3 + (B1.x - A1.x);
        float r5  = r4 + (B1.y - A1.y);
        float r6  = r5 + (B1.z - A1.z);
        float r7  = r6 + (B1.w - A1.w);
        float r8  = r7 + (B2.x - A2.x);
        float r9  = r8 + (B2.y - A2.y);
        float r10 = r9 + (B2.z - A2.z);
        float r11 = r10 + (B2.w - A2.w);
        // one 6-step exclusive wave scan of lane totals
        float total = r11;
        float incl = total;
        #pragma unroll
        for (int d = 1; d < 64; d <<= 1) {
            float u = __shfl_up(incl, d, 64);
            if (lane >= d) incl += u;
        }
        float excl = incl - total;
        float* Prow = P + r * PSTR + 12 * lane;
        float4 w0 = { r0 + excl, r1 + excl, r2 + excl, r3 + excl };
        float4 w1 = { r4 + excl, r5 + excl, r6 + excl, r7 + excl };
        float4 w2 = { r8 + excl, r9 + excl, r10 + excl, r11 + excl };
        *(float4*)(Prow)     = w0;
        *(float4*)(Prow + 4) = w1;
        *(float4*)(Prow + 8) = w2;
    }
    __syncthreads();

    // ---- Phase B+C: per-box accumulation, contiguous write -----------------
    const int* mXb = metaX + (size_t)b * NN;
    const int* mYb = metaY + (size_t)b * NN;
    float* outp = detPartial + ((size_t)b * NBAND + band) * NN;
    for (int j = t; j < NN; j += 256) {
        int mx = mXb[j], my = mYb[j];
        int y1 = my & 0xffff, y2 = my >> 16;
        int lo = max(y1, y0), hi = min(y2, y0 + BAND);
        float acc = 0.f;
        if (lo < hi) {
            int x1 = mx & 0xffff, x2m1 = mx >> 16;
            const float* Pp = P + (lo - y0) * PSTR;
            if (x1 > 0) {
                for (int r = lo; r < hi; ++r, Pp += PSTR) acc += Pp[x2m1] - Pp[x1 - 1];
            } else {
                for (int r = lo; r < hi; ++r, Pp += PSTR) acc += Pp[x2m1];
            }
        }
        outp[j] = acc;
    }
}

// ---------------------------------------------------------------------------
// K2: blocks 0..18 finalize det term (sum 96 band partials, coalesced);
//     blocks 19..34 do plate IoU + OCR for batch b = blk-19.
// ---------------------------------------------------------------------------
__global__ __launch_bounds__(256) void k_small(const float* __restrict__ det_boxes,
                                               const float* __restrict__ logits,
                                               const float* __restrict__ plate_boxes,
                                               const float* __restrict__ plate_conf,
                                               const float* __restrict__ ocr,
                                               const float* __restrict__ detPartial,
                                               const int* __restrict__ metaX,
                                               const int* __restrict__ metaY,
                                               float* __restrict__ detPart,
                                               float* __restrict__ platePart,
                                               float* __restrict__ plateCnt,
                                               float* __restrict__ ocrPart) {
    const int t = threadIdx.x;
    if (blockIdx.x < NDETBLK) {
        const int idx = blockIdx.x * 256 + t;
        float contrib = 0.f;
        if (idx < BB * NN) {
            const int b = idx / NN, j = idx % NN;
            int mx = metaX[idx], my = metaY[idx];
            if (my != 0) {
                const float* lg = logits + (size_t)idx * 7;
                float m = lg[0];
                #pragma unroll
                for (int i = 1; i < 7; ++i) m = fmaxf(m, lg[i]);
                float ssum = 0.f;
                #pragma unroll
                for (int i = 0; i < 7; ++i) ssum += expf(lg[i] - m);
                float conf = 1.f / ssum;
                int x1 = mx & 0xffff, x2m1 = mx >> 16;
                int y1 = my & 0xffff, y2 = my >> 16;
                const float* pp = detPartial + (size_t)b * NBAND * NN + j;
                float s0 = 0.f, s1 = 0.f;
                for (int g2 = 0; g2 < NBAND; g2 += 2) {
                    s0 += pp[(size_t)g2 * NN];
                    s1 += pp[(size_t)(g2 + 1) * NN];
                }
                float Sb = s0 + s1;
                float area = (float)((y2 - y1) * (x2m1 + 1 - x1));
                contrib = relu_f(Sb / area) * conf;
            }
        }
        __shared__ float red[256];
        red[t] = contrib;
        __syncthreads();
        for (int k = 128; k > 0; k >>= 1) {
            if (t < k) red[t] += red[t + k];
            __syncthreads();
        }
        if (t == 0) detPart[blockIdx.x] = red[0];
    } else {
        const float CONF_TH = 0.3f, MIN_IOU = 0.5f, OCR_TH = 0.7f;
        const int b = blockIdx.x - NDETBLK;

        __shared__ float vx1[NN], vy1[NN], vx2[NN], vy2[NN], va[NN], vcf[NN];
        __shared__ int anyv;
        __shared__ float redf[256];
        __shared__ int   redi[256];

        if (t == 0) anyv = 0;
        __syncthreads();

        for (int j = t; j < NN; j += 256) {
            const float* bxp = det_boxes + ((size_t)b * NN + j) * 4;
            float cx = bxp[0], cy = bxp[1], w = bxp[2], h = bxp[3];
            float x1 = cx - w * 0.5f, y1 = cy - h * 0.5f;
            float x2 = cx + w * 0.5f, y2 = cy + h * 0.5f;
            vx1[j] = x1; vy1[j] = y1; vx2[j] = x2; vy2[j] = y2;
            va[j] = (x2 - x1) * (y2 - y1);
            const float* lg = logits + ((size_t)b * NN + j) * 7;
            float m = lg[0];
            #pragma unroll
            for (int i = 1; i < 7; ++i) m = fmaxf(m, lg[i]);
            float sum = 0.f;
            #pragma unroll
            for (int i = 0; i < 7; ++i) sum += expf(lg[i] - m);
            float cc = 1.f / sum;
            vcf[j] = cc;
            if (cc > CONF_TH) atomicOr(&anyv, 1);
        }
        __syncthreads();

        float term = 0.f; int pv = 0; float pcf = -1e30f;
        if (t < PP) {
            const float* bxp = plate_boxes + ((size_t)b * PP + t) * 4;
            float cx = bxp[0], cy = bxp[1], w = bxp[2], h = bxp[3];
            float px1 = cx - w * 0.5f, py1 = cy - h * 0.5f;
            float px2 = cx + w * 0.5f, py2 = cy + h * 0.5f;
            float a1 = (px2 - px1) * (py2 - py1);
            pcf = plate_conf[b * PP + t];
            pv = (pcf > CONF_TH) ? 1 : 0;
            float max_iou = -1.f;
            for (int j = 0; j < NN; ++j) {
                if (vcf[j] > CONF_TH) {
                    float ltx = fmaxf(px1, vx1[j]);
                    float lty = fmaxf(py1, vy1[j]);
                    float rbx = fminf(px2, vx2[j]);
                    float rby = fminf(py2, vy2[j]);
                    float iw = fmaxf(rbx - ltx, 0.f);
                    float ih = fmaxf(rby - lty, 0.f);
                    float inter = iw * ih;
                    float uni = a1 + va[j] - inter;
                    float iou = inter / (uni + 1e-8f);
                    max_iou = fmaxf(max_iou, iou);
                }
            }
            if (pv) term = relu_f(MIN_IOU - max_iou) * pcf;
        }

        redf[t] = term; redi[t] = pv;
        __syncthreads();
        for (int k = 128; k > 0; k >>= 1) {
            if (t < k) { redf[t] += redf[t + k]; redi[t] += redi[t + k]; }
            __syncthreads();
        }
        float termsum = redf[0];
        int   cnt     = redi[0];
        __syncthreads();

        float osum = 0.f;
        if (t < LL) {
            const float* op = ocr + ((size_t)b * LL + t) * 37;
            float m = op[0];
            #pragma unroll
            for (int i = 1; i < 37; ++i) m = fmaxf(m, op[i]);
            osum = m;
        }
        redf[t] = osum;
        __syncthreads();
        for (int k = 128; k > 0; k >>= 1) {
            if (t < k) redf[t] += redf[t + k];
            __syncthreads();
        }
        float avg_ocr = redf[0] / (float)LL;
        __syncthreads();

        redf[t] = (t < PP) ? pcf : -1e30f;
        __syncthreads();
        for (int k = 128; k > 0; k >>= 1) {
            if (t < k) redf[t] = fmaxf(redf[t], redf[t + k]);
            __syncthreads();
        }
        float max_plate = redf[0];

        if (t == 0) {
            platePart[b] = (cnt > 0 && anyv) ? termsum : 0.f;
            plateCnt[b]  = (float)cnt;
            ocrPart[b]   = (avg_ocr > OCR_TH) ? relu_f(avg_ocr - max_plate) : 0.f;
        }
    }
}

// ---------------------------------------------------------------------------
// K3: final deterministic combine.
// ---------------------------------------------------------------------------
__global__ __launch_bounds__(64) void k_final(const float* __restrict__ detPart,
                                              const float* __restrict__ platePart,
                                              const float* __restrict__ plateCnt,
                                              const float* __restrict__ ocrPart,
                                              float* __restrict__ out) {
    if (threadIdx.x == 0 && blockIdx.x == 0) {
        double ds = 0.0;
        for (int i = 0; i < NDETBLK; ++i) ds += (double)detPart[i];
        double ps = 0.0, cnt = 0.0, os = 0.0;
        for (int b = 0; b < BB; ++b) {
            ps  += (double)platePart[b];
            cnt += (double)plateCnt[b];
            os  += (double)ocrPart[b];
        }
        float det_seg   = (float)ds / (float)(BB * NN);
        float plate_det = (float)ps / fmaxf((float)cnt, 1.f);
        float ocr_plate = (float)os / (float)BB;
        out[0] = 0.1f * det_seg + 0.1f * plate_det + 0.1f * ocr_plate;
    }
}

extern "C" void kernel_launch(void* const* d_in, const int* in_sizes, int n_in,
                              void* d_out, int out_size, void* d_ws, size_t ws_size,
                              hipStream_t stream) {
    const float* det_boxes   = (const float*)d_in[0];
    const float* det_logits  = (const float*)d_in[1];
    const float* seg_masks   = (const float*)d_in[2];
    const float* plate_boxes = (const float*)d_in[3];
    const float* plate_conf  = (const float*)d_in[4];
    const float* ocr_probs   = (const float*)d_in[5];
    float* out = (float*)d_out;

    // workspace layout
    float* detPartial = (float*)d_ws;                          // B*NBAND*N = 460800 f
    float* detPart    = detPartial + (size_t)BB * NBAND * NN;  // 19
    float* platePart  = detPart + NDETBLK;                     // 16
    float* plateCnt   = platePart + BB;                        // 16
    float* ocrPart    = plateCnt + BB;                         // 16
    int*   metaX      = (int*)(ocrPart + BB);                  // 4800
    int*   metaY      = metaX + BB * NN;                       // 4800

    k_meta<<<NDETBLK, 256, 0, stream>>>(det_boxes, det_logits, metaX, metaY);
    k_band<<<BB * NBAND, 256, 0, stream>>>(seg_masks, metaX, metaY, detPartial);
    k_small<<<NDETBLK + BB, 256, 0, stream>>>(det_boxes, det_logits, plate_boxes,
                                              plate_conf, ocr_probs, detPartial,
                                              metaX, metaY,
                                              detPart, platePart, plateCnt, ocrPart);
    k_final<<<1, 64, 0, stream>>>(detPart, platePart, plateCnt, ocrPart, out);
}